// Round 9
// baseline (353.567 us; speedup 1.0000x reference)
//
#include <hip/hip_runtime.h>

typedef short short8 __attribute__((ext_vector_type(8)));
typedef float v4f __attribute__((ext_vector_type(4)));
typedef float v16f __attribute__((ext_vector_type(16)));

#define LOG2E 1.4426950408889634f

__device__ __forceinline__ unsigned short f2bf(float f) {
  unsigned int u = __float_as_uint(f);
  u += 0x7fff + ((u >> 16) & 1);   // round-to-nearest-even
  return (unsigned short)(u >> 16);
}
__device__ __forceinline__ float b2f(unsigned short h) {
  return __uint_as_float(((unsigned int)h) << 16);
}
__device__ __forceinline__ void gl_lds16(const void* g, void* l) {
  __builtin_amdgcn_global_load_lds((const __attribute__((address_space(1))) void*)g,
                                   (__attribute__((address_space(3))) void*)l, 16, 0, 0);
}

// ---------------- fused prep: f32->bf16 cvt of X + 4 weight transposes ----------------
// grid 11264: [0,8192) cvt x; [8192,9216) wq; [9216,9728) wk; [9728,10240) wv; [10240,11264) wo
__global__ __launch_bounds__(256) void prep_k(const float* __restrict__ x,
                                              unsigned short* __restrict__ Xb,
                                              const float* __restrict__ wq,
                                              const float* __restrict__ wk,
                                              const float* __restrict__ wv,
                                              const float* __restrict__ wo,
                                              unsigned short* __restrict__ WqkvT,
                                              unsigned short* __restrict__ WoT) {
  __shared__ float tile[64][65];
  const int bid = blockIdx.x, t = threadIdx.x;
  if (bid < 8192) {
    int i = (bid * 256 + t) * 4;
    float4 v = *(const float4*)(x + i);
    ushort4 o;
    o.x = f2bf(v.x); o.y = f2bf(v.y); o.z = f2bf(v.z); o.w = f2bf(v.w);
    *(ushort4*)(Xb + i) = o;
    return;
  }
  const float* src; unsigned short* dst; int srcCols, bx, by;
  if (bid < 9216)      { int g = bid - 8192;  src = wq; dst = WqkvT;                         srcCols = 2048; bx = g & 31, by = g >> 5; }
  else if (bid < 9728) { int g = bid - 9216;  src = wk; dst = WqkvT + (size_t)2048 * 2048;   srcCols = 1024; bx = g & 15, by = g >> 4; }
  else if (bid < 10240){ int g = bid - 9728;  src = wv; dst = WqkvT + (size_t)3072 * 2048;   srcCols = 1024; bx = g & 15, by = g >> 4; }
  else                 { int g = bid - 10240; src = wo; dst = WoT;                           srcCols = 2048; bx = g & 31, by = g >> 5; }
  const int c0 = bx * 64;   // src col = dst row
  const int r0 = by * 64;   // src row = dst col
#pragma unroll
  for (int i = 0; i < 16; ++i) {
    int idx = t + i * 256; int r = idx >> 6, c = idx & 63;
    tile[r][c] = src[(size_t)(r0 + r) * srcCols + c0 + c];
  }
  __syncthreads();
#pragma unroll
  for (int i = 0; i < 16; ++i) {
    int idx = t + i * 256; int r = idx >> 6, c = idx & 63;
    dst[(size_t)(c0 + r) * 2048 + r0 + c] = f2bf(tile[c][r]);
  }
}

// ---------------- GEMM (128^2 tile, proven): C[M,N] = A[M,K] * Bt[N,K]^T ----------------
template <bool OUT_BF16>
__global__ __launch_bounds__(256) void gemm_bt(const unsigned short* __restrict__ A,
                                               const unsigned short* __restrict__ Bt,
                                               void* __restrict__ Cv,
                                               int M, int N, int K) {
  __shared__ __align__(16) unsigned short As[2][128 * 32];
  __shared__ __align__(16) unsigned short Bs[2][128 * 32];
  const int t = threadIdx.x;
  const int wave = t >> 6, lane = t & 63, quad = lane >> 4, l16 = lane & 15;
  const int tm = blockIdx.y * 128, tn = blockIdx.x * 128;
  const int wm = (wave >> 1) * 64, wn = (wave & 1) * 64;
  v4f acc[4][4];
#pragma unroll
  for (int i = 0; i < 4; ++i)
#pragma unroll
    for (int j = 0; j < 4; ++j) acc[i][j] = (v4f){0.f, 0.f, 0.f, 0.f};

  const int swz = (l16 >> 1) & 3;

  const int s0 = t, s1 = 256 + t;
  const unsigned short* pa0 = A + (size_t)(tm + (s0 >> 2)) * K + ((s0 & 3) ^ ((s0 >> 3) & 3)) * 8;
  const unsigned short* pa1 = A + (size_t)(tm + (s1 >> 2)) * K + ((s1 & 3) ^ ((s1 >> 3) & 3)) * 8;
  const unsigned short* pb0 = Bt + (size_t)(tn + (s0 >> 2)) * K + ((s0 & 3) ^ ((s0 >> 3) & 3)) * 8;
  const unsigned short* pb1 = Bt + (size_t)(tn + (s1 >> 2)) * K + ((s1 & 3) ^ ((s1 >> 3) & 3)) * 8;
  const int dOff0 = (wave * 64) * 8;
  const int dOff1 = (256 + wave * 64) * 8;

  gl_lds16(pa0, &As[0][dOff0]); gl_lds16(pa1, &As[0][dOff1]);
  gl_lds16(pb0, &Bs[0][dOff0]); gl_lds16(pb1, &Bs[0][dOff1]);
  pa0 += 32; pa1 += 32; pb0 += 32; pb1 += 32;

  const int nit = K >> 5;
  for (int it = 0; it < nit; ++it) {
    __syncthreads();
    const int cur = it & 1;
    if (it + 1 < nit) {
      const int nxt = cur ^ 1;
      gl_lds16(pa0, &As[nxt][dOff0]); gl_lds16(pa1, &As[nxt][dOff1]);
      gl_lds16(pb0, &Bs[nxt][dOff0]); gl_lds16(pb1, &Bs[nxt][dOff1]);
      pa0 += 32; pa1 += 32; pb0 += 32; pb1 += 32;
    }
    short8 af[4], bf[4];
#pragma unroll
    for (int mt = 0; mt < 4; ++mt)
      af[mt] = *(const short8*)(&As[cur][(wm + mt * 16 + l16) * 32 + (quad ^ swz) * 8]);
#pragma unroll
    for (int nt = 0; nt < 4; ++nt)
      bf[nt] = *(const short8*)(&Bs[cur][(wn + nt * 16 + l16) * 32 + (quad ^ swz) * 8]);
#pragma unroll
    for (int mt = 0; mt < 4; ++mt)
#pragma unroll
      for (int nt = 0; nt < 4; ++nt)
        acc[mt][nt] = __builtin_amdgcn_mfma_f32_16x16x32_bf16(af[mt], bf[nt], acc[mt][nt], 0, 0, 0);
  }

#pragma unroll
  for (int mt = 0; mt < 4; ++mt)
#pragma unroll
    for (int nt = 0; nt < 4; ++nt)
#pragma unroll
      for (int r = 0; r < 4; ++r) {
        int row = tm + wm + mt * 16 + quad * 4 + r;
        int col = tn + wn + nt * 16 + l16;
        float v = acc[mt][nt][r];
        if (OUT_BF16) ((unsigned short*)Cv)[(size_t)row * N + col] = f2bf(v);
        else          ((float*)Cv)[(size_t)row * N + col] = v;
      }
}

// ---------------- GEMM 256^2 tile, 8-wave, 4-phase, PIPELINED fragment reads ----------------
// ds_reads for phase P are issued inside phase P-1's MFMA region (after lgkm0, before MFMA),
// so LDS-read latency hides under the ~550-cyc MFMA window instead of ping-ponging:
//   P4(kt) region reads aflo/bflo(kt+1) from buf[nxt]  (valid: vmcnt(4) drained h1(kt+1))
//   P1(kt) region reads bfhi(kt); P2 region reads afhi(kt); P3 reads nothing.
// WAR: every read completes (next lgkm0) >=1 barrier before the in-place STG overwriting
// its rows; read-dest registers are disjoint from the host region's MFMA operands.
template <bool OUT_BF16>
__global__ __launch_bounds__(512, 2) void gemm256(const unsigned short* __restrict__ A,
                                                  const unsigned short* __restrict__ Bt,
                                                  void* __restrict__ Cv,
                                                  int M, int N, int K) {
  __shared__ __align__(16) unsigned short As[2][256 * 64];   // 64 KB
  __shared__ __align__(16) unsigned short Bs[2][256 * 64];   // 64 KB
  const int t = threadIdx.x;
  const int wave = t >> 6, lane = t & 63, quad = lane >> 4, l16 = lane & 15;
  const int wr = wave >> 2, wc = wave & 3;

  const int gx = N >> 8;
  int id = blockIdx.y * gridDim.x + blockIdx.x;
  const int nwg = gridDim.x * gridDim.y;
  id = (id & 7) * (nwg >> 3) + (id >> 3);
  const int tm = (id / gx) << 8, tn = (id % gx) << 8;

  v4f acc[8][4];
#pragma unroll
  for (int i = 0; i < 8; ++i)
#pragma unroll
    for (int j = 0; j < 4; ++j) acc[i][j] = (v4f){0.f, 0.f, 0.f, 0.f};

  const int s0 = t, s1 = 512 + t;
  const size_t hA = (size_t)128 * K;
  const unsigned short* a0 = A + (size_t)(tm + (s0 >> 3)) * K + ((s0 & 7) ^ ((s0 >> 3) & 7)) * 8;
  const unsigned short* a1 = A + (size_t)(tm + (s1 >> 3)) * K + ((s1 & 7) ^ ((s1 >> 3) & 7)) * 8;
  const unsigned short* b0 = Bt + (size_t)(tn + (s0 >> 3)) * K + ((s0 & 7) ^ ((s0 >> 3) & 7)) * 8;
  const unsigned short* b1 = Bt + (size_t)(tn + (s1 >> 3)) * K + ((s1 & 7) ^ ((s1 >> 3) & 7)) * 8;
  const int d0 = (wave * 64) * 8;
  const int d1 = (512 + wave * 64) * 8;

#define STG_A(buf, h, koff)                                         \
  do {                                                              \
    gl_lds16(a0 + (size_t)(h) * hA + (koff), &As[buf][(h) * 8192 + d0]); \
    gl_lds16(a1 + (size_t)(h) * hA + (koff), &As[buf][(h) * 8192 + d1]); \
  } while (0)
#define STG_B(buf, h, koff)                                         \
  do {                                                              \
    gl_lds16(b0 + (size_t)(h) * hA + (koff), &Bs[buf][(h) * 8192 + d0]); \
    gl_lds16(b1 + (size_t)(h) * hA + (koff), &Bs[buf][(h) * 8192 + d1]); \
  } while (0)

  const int aBase = (wr * 128 + l16) * 64;
  const int bBase = (wc * 64 + l16) * 64;
  const int c0 = (quad ^ (l16 & 7)) * 8;
  const int c1 = ((4 + quad) ^ (l16 & 7)) * 8;

  const int nkt = K >> 6;

  STG_A(0, 0, 0); STG_A(0, 1, 0);
  STG_B(0, 0, 0); STG_B(0, 1, 0);
  STG_B(1, 0, 64); STG_A(1, 0, 64);
  asm volatile("s_waitcnt vmcnt(4)" ::: "memory");   // kt0's 8 loads landed
  __builtin_amdgcn_s_barrier();

  short8 aflo[4][2], afhi[4][2], bflo[2][2], bfhi[2][2];
  // pre-read kt0 P1 operands (only non-overlapped read block)
#pragma unroll
  for (int m = 0; m < 4; ++m) {
    aflo[m][0] = *(const short8*)(&As[0][aBase + m * 1024 + c0]);
    aflo[m][1] = *(const short8*)(&As[0][aBase + m * 1024 + c1]);
  }
#pragma unroll
  for (int n = 0; n < 2; ++n) {
    bflo[n][0] = *(const short8*)(&Bs[0][bBase + n * 1024 + c0]);
    bflo[n][1] = *(const short8*)(&Bs[0][bBase + n * 1024 + c1]);
  }

  for (int kt = 0; kt < nkt; ++kt) {
    const int cur = kt & 1, nxt = cur ^ 1;
    const int koff = kt << 6;

    // ---------- phase 1: Q00 (aflo x bflo); read bfhi(kt); stage h1(kt+1) ----------
    if (kt + 1 < nkt) { STG_A(nxt, 1, koff + 64); STG_B(nxt, 1, koff + 64); }
    __builtin_amdgcn_s_barrier();
    asm volatile("s_waitcnt lgkmcnt(0)" ::: "memory");
    __builtin_amdgcn_s_setprio(1);
#pragma unroll
    for (int n = 0; n < 2; ++n) {
      bfhi[n][0] = *(const short8*)(&Bs[cur][bBase + (2 + n) * 1024 + c0]);
      bfhi[n][1] = *(const short8*)(&Bs[cur][bBase + (2 + n) * 1024 + c1]);
    }
#pragma unroll
    for (int m = 0; m < 4; ++m)
#pragma unroll
      for (int n = 0; n < 2; ++n) {
        acc[m][n] = __builtin_amdgcn_mfma_f32_16x16x32_bf16(aflo[m][0], bflo[n][0], acc[m][n], 0, 0, 0);
        acc[m][n] = __builtin_amdgcn_mfma_f32_16x16x32_bf16(aflo[m][1], bflo[n][1], acc[m][n], 0, 0, 0);
      }
    __builtin_amdgcn_s_setprio(0);
    __builtin_amdgcn_s_barrier();

    // ---------- phase 2: Q01 (aflo x bfhi); read afhi(kt) ----------
    __builtin_amdgcn_s_barrier();
    asm volatile("s_waitcnt lgkmcnt(0)" ::: "memory");
    __builtin_amdgcn_s_setprio(1);
#pragma unroll
    for (int m = 0; m < 4; ++m) {
      afhi[m][0] = *(const short8*)(&As[cur][aBase + (4 + m) * 1024 + c0]);
      afhi[m][1] = *(const short8*)(&As[cur][aBase + (4 + m) * 1024 + c1]);
    }
#pragma unroll
    for (int m = 0; m < 4; ++m)
#pragma unroll
      for (int n = 0; n < 2; ++n) {
        acc[m][2 + n] = __builtin_amdgcn_mfma_f32_16x16x32_bf16(aflo[m][0], bfhi[n][0], acc[m][2 + n], 0, 0, 0);
        acc[m][2 + n] = __builtin_amdgcn_mfma_f32_16x16x32_bf16(aflo[m][1], bfhi[n][1], acc[m][2 + n], 0, 0, 0);
      }
    __builtin_amdgcn_s_setprio(0);
    __builtin_amdgcn_s_barrier();

    // ---------- phase 3: Q10 (afhi x bflo); stage B-h0(kt+2) ----------
    if (kt + 2 < nkt) STG_B(cur, 0, koff + 128);
    __builtin_amdgcn_s_barrier();
    asm volatile("s_waitcnt lgkmcnt(0)" ::: "memory");
    __builtin_amdgcn_s_setprio(1);
#pragma unroll
    for (int m = 0; m < 4; ++m)
#pragma unroll
      for (int n = 0; n < 2; ++n) {
        acc[4 + m][n] = __builtin_amdgcn_mfma_f32_16x16x32_bf16(afhi[m][0], bflo[n][0], acc[4 + m][n], 0, 0, 0);
        acc[4 + m][n] = __builtin_amdgcn_mfma_f32_16x16x32_bf16(afhi[m][1], bflo[n][1], acc[4 + m][n], 0, 0, 0);
      }
    __builtin_amdgcn_s_setprio(0);
    __builtin_amdgcn_s_barrier();

    // ---------- phase 4: Q11 (afhi x bfhi); stage A-h0(kt+2); read aflo/bflo(kt+1) ----------
    if (kt + 2 < nkt) {
      STG_A(cur, 0, koff + 128);
      asm volatile("s_waitcnt vmcnt(4)" ::: "memory");   // h1(kt+1) landed; kt+2 h0s in flight
    } else {
      asm volatile("s_waitcnt vmcnt(0)" ::: "memory");
    }
    __builtin_amdgcn_s_barrier();
    __builtin_amdgcn_s_setprio(1);
    if (kt + 1 < nkt) {
#pragma unroll
      for (int m = 0; m < 4; ++m) {
        aflo[m][0] = *(const short8*)(&As[nxt][aBase + m * 1024 + c0]);
        aflo[m][1] = *(const short8*)(&As[nxt][aBase + m * 1024 + c1]);
      }
#pragma unroll
      for (int n = 0; n < 2; ++n) {
        bflo[n][0] = *(const short8*)(&Bs[nxt][bBase + n * 1024 + c0]);
        bflo[n][1] = *(const short8*)(&Bs[nxt][bBase + n * 1024 + c1]);
      }
    }
#pragma unroll
    for (int m = 0; m < 4; ++m)
#pragma unroll
      for (int n = 0; n < 2; ++n) {
        acc[4 + m][2 + n] = __builtin_amdgcn_mfma_f32_16x16x32_bf16(afhi[m][0], bfhi[n][0], acc[4 + m][2 + n], 0, 0, 0);
        acc[4 + m][2 + n] = __builtin_amdgcn_mfma_f32_16x16x32_bf16(afhi[m][1], bfhi[n][1], acc[4 + m][2 + n], 0, 0, 0);
      }
    __builtin_amdgcn_s_setprio(0);
    __builtin_amdgcn_s_barrier();
  }
#undef STG_A
#undef STG_B

#pragma unroll
  for (int mf = 0; mf < 8; ++mf)
#pragma unroll
    for (int nf = 0; nf < 4; ++nf)
#pragma unroll
      for (int r = 0; r < 4; ++r) {
        int row = tm + wr * 128 + mf * 16 + quad * 4 + r;
        int col = tn + wc * 64 + nf * 16 + l16;
        float v = acc[mf][nf][r];
        if (OUT_BF16) ((unsigned short*)Cv)[(size_t)row * N + col] = f2bf(v);
        else          ((float*)Cv)[(size_t)row * N + col] = v;
      }
}

// ---------------- fused RoPE (Q,K dwords) + V transpose (disjoint QKV columns) ----------------
// grid 5120: [0,4096) rope rows; [4096,5120) V-transpose tiles.
__global__ __launch_bounds__(256) void rope_tv_k(unsigned short* __restrict__ qkv,
                                                 const float* __restrict__ freqs,
                                                 unsigned short* __restrict__ vt) {
  __shared__ unsigned short tile[64][65];
  const int bid = blockIdx.x, t = threadIdx.x;
  if (bid < 4096) {
    const int bs = bid;                 // b*2048 + s
    const int s = bs & 2047;
    const float qscale = 0.08838834764831845f;  // 1/sqrt(128)
    unsigned int* row = (unsigned int*)(qkv + (size_t)bs * 4096);
    const float2* fr2 = (const float2*)(freqs + s * 128);
#pragma unroll
    for (int k = 0; k < 6; ++k) {
      int d = t + k * 256;              // dword index 0..1535 (Q,K only; V untouched)
      float sc = (d < 1024) ? qscale : 1.0f;
      float2 cs = fr2[d & 63];          // (cos, sin)
      unsigned int w = row[d];
      float x0 = b2f((unsigned short)(w & 0xffffu));
      float x1 = b2f((unsigned short)(w >> 16));
      float y0 = (x0 * cs.y - x1 * cs.x) * sc;
      float y1 = (x0 * cs.x + x1 * cs.y) * sc;
      row[d] = ((unsigned int)f2bf(y1) << 16) | (unsigned int)f2bf(y0);
    }
    return;
  }
  const int g = bid - 4096;
  const int s0 = (g & 31) * 64, d0 = ((g >> 5) & 1) * 64;
  const int bk = g >> 6; const int b = bk >> 3, kv = bk & 7;
#pragma unroll
  for (int i = 0; i < 16; ++i) {
    int idx = t + i * 256; int r = idx >> 6, c = idx & 63;
    tile[r][c] = qkv[(size_t)(b * 2048 + s0 + r) * 4096 + 3072 + kv * 128 + d0 + c];
  }
  __syncthreads();
#pragma unroll
  for (int i = 0; i < 16; ++i) {
    int idx = t + i * 256; int r = idx >> 6, c = idx & 63;
    vt[((size_t)bk * 128 + d0 + r) * 2048 + s0 + c] = tile[c][r];
  }
}

// ---------------- causal flash attention, 32x32 MFMA, O^T, KVBLK=64 (R5-proven) ----------------
__global__ __launch_bounds__(256, 2) void attn_k(const unsigned short* __restrict__ qkv,
                                                 const unsigned short* __restrict__ vt,
                                                 unsigned short* __restrict__ Ob) {
  __shared__ __align__(16) unsigned short Ks[2][64 * 128];   // [key][d], 16 chunks/row
  __shared__ __align__(16) unsigned short Vs[2][128 * 64];   // [d][key],  8 chunks/row
  const int t = threadIdx.x, wave = t >> 6, lane = t & 63;
  const int l31 = lane & 31, hh2 = lane >> 5;
  const int hd = blockIdx.y, b = blockIdx.z;
  const int qblk = b ? blockIdx.x : 15 - blockIdx.x;   // complementary co-resident pairs
  const int kv = hd >> 1;
  const int q0 = qblk * 128;
  const int qrel = wave * 32 + l31;
  const int qrow = q0 + qrel;

  auto stage = [&](int jt, int buf) {
#pragma unroll
    for (int issue = 0; issue < 4; ++issue) {
      int s = issue * 256 + t;                 // K slot 0..1023
      int row = s >> 4;                        // key 0..63
      int src = ((s & 15) ^ (row & 15)) * 8;   // pre-swizzled source chunk
      gl_lds16(qkv + (size_t)(b * 2048 + jt * 64 + row) * 4096 + 2048 + kv * 128 + src,
               &Ks[buf][(issue * 256 + wave * 64) * 8]);
    }
#pragma unroll
    for (int issue = 0; issue < 4; ++issue) {
      int s = issue * 256 + t;                 // V slot 0..1023
      int row = s >> 3;                        // d 0..127
      int src = ((s & 7) ^ (row & 7)) * 8;
      gl_lds16(vt + ((size_t)(b * 8 + kv) * 128 + row) * 2048 + jt * 64 + src,
               &Vs[buf][(issue * 256 + wave * 64) * 8]);
    }
  };

  short8 qf[8];
  {
    const unsigned short* qp = qkv + (size_t)(b * 2048 + qrow) * 4096 + hd * 128 + hh2 * 8;
#pragma unroll
    for (int ks = 0; ks < 8; ++ks) qf[ks] = *(const short8*)(qp + ks * 16);
  }
  stage(0, 0);

  v16f oa[4];
#pragma unroll
  for (int i = 0; i < 4; ++i)
#pragma unroll
    for (int r = 0; r < 16; ++r) oa[i][r] = 0.f;
  float m_s = -3.0e38f, l_s = 0.f;

  const int ntl = 2 * (qblk + 1);   // 64-key tiles
  for (int jt = 0; jt < ntl; ++jt) {
    const int cur = jt & 1;
    if (jt + 1 < ntl) {
      stage(jt + 1, cur ^ 1);
      asm volatile("s_waitcnt vmcnt(8)" ::: "memory");   // tile jt landed; jt+1 in flight
    } else {
      asm volatile("s_waitcnt vmcnt(0)" ::: "memory");
    }
    __builtin_amdgcn_s_barrier();

    // ---- QK^T: S^T tiles, rows = keys (kt*32 + map), cols = q (l31) ----
    v16f st[2];
#pragma unroll
    for (int i = 0; i < 2; ++i)
#pragma unroll
      for (int r = 0; r < 16; ++r) st[i][r] = 0.f;
#pragma unroll
    for (int ks = 0; ks < 8; ++ks)
#pragma unroll
      for (int kt = 0; kt < 2; ++kt) {
        int row = kt * 32 + l31;
        short8 kf = *(const short8*)(
            &Ks[cur][row * 128 + (((ks * 2 + hh2) ^ (row & 15)) * 8)]);
        st[kt] = __builtin_amdgcn_mfma_f32_32x32x16_bf16(kf, qf[ks], st[kt], 0, 0, 0);
      }

    // ---- mask (only tiles overlapping the diagonal) + row max ----
    float mx0 = -3.0e38f, mx1 = -3.0e38f;
    if (jt >= 2 * qblk) {
      const int rel = qrel - (jt * 64 - q0);   // key-local threshold
#pragma unroll
      for (int kt = 0; kt < 2; ++kt)
#pragma unroll
        for (int r = 0; r < 16; ++r) {
          int key = kt * 32 + (r & 3) + 8 * (r >> 2) + 4 * hh2;
          float v = st[kt][r];
          if (key > rel) v = -1.0e30f;
          st[kt][r] = v;
          if (r & 1) mx1 = fmaxf(mx1, v); else mx0 = fmaxf(mx0, v);
        }
    } else {
#pragma unroll
      for (int kt = 0; kt < 2; ++kt)
#pragma unroll
        for (int r = 0; r < 16; ++r) {
          if (r & 1) mx1 = fmaxf(mx1, st[kt][r]); else mx0 = fmaxf(mx0, st[kt][r]);
        }
    }
    float mx = fmaxf(mx0, mx1);
    mx = fmaxf(mx, __shfl_xor(mx, 32));   // combine the two key-halves of this qrow

    // ---- defer-max rescale (rare) ----
    if (__ballot(mx > m_s + 8.0f)) {
      float mn = fmaxf(m_s, mx);
      float alpha = exp2f((m_s - mn) * LOG2E);
      m_s = mn;
#pragma unroll
      for (int i = 0; i < 4; ++i)
#pragma unroll
        for (int r = 0; r < 16; ++r) oa[i][r] *= alpha;
      l_s *= alpha;
    }

    // ---- exp + pack P to bf16 dwords ----
    float lt0 = 0.f, lt1 = 0.f;
    unsigned int PD[2][8];
#pragma unroll
    for (int kt = 0; kt < 2; ++kt)
#pragma unroll
      for (int j = 0; j < 8; ++j) {
        float p0 = exp2f((st[kt][2 * j]     - m_s) * LOG2E);
        float p1 = exp2f((st[kt][2 * j + 1] - m_s) * LOG2E);
        lt0 += p0; lt1 += p1;
        unsigned int pd;
        asm("v_cvt_pk_bf16_f32 %0, %1, %2" : "=v"(pd) : "v"(p0), "v"(p1));
        PD[kt][j] = pd;
      }
    float lt = lt0 + lt1;
    lt += __shfl_xor(lt, 32);
    l_s += lt;

    // ---- exchange complementary key-halves (lane l <-> l+32) ----
    unsigned int XD[2][8];
#pragma unroll
    for (int kt = 0; kt < 2; ++kt)
#pragma unroll
      for (int j = 0; j < 8; ++j) XD[kt][j] = __shfl_xor(PD[kt][j], 32);

    // ---- PV: O^T += V' * P^T (contraction over 64 keys = 4 k-steps) ----
#pragma unroll
    for (int ks = 0; ks < 4; ++ks) {
      const int tt = ks >> 1, w4 = (ks & 1) * 4;
      union { unsigned int u[4]; short8 s8; } pf;
      pf.u[0] = hh2 ? XD[tt][w4 + 2] : PD[tt][w4 + 0];
      pf.u[1] = hh2 ? XD[tt][w4 + 3] : PD[tt][w4 + 1];
      pf.u[2] = hh2 ? PD[tt][w4 + 2] : XD[tt][w4 + 0];
      pf.u[3] = hh2 ? PD[tt][w4 + 3] : XD[tt][w4 + 1];
#pragma unroll
      for (int dt = 0; dt < 4; ++dt) {
        int row = dt * 32 + l31;
        short8 vf = *(const short8*)(
            &Vs[cur][row * 64 + (((ks * 2 + hh2) ^ (row & 7)) * 8)]);
        oa[dt] = __builtin_amdgcn_mfma_f32_32x32x16_bf16(vf, pf.s8, oa[dt], 0, 0, 0);
      }
    }
    __builtin_amdgcn_s_barrier();   // all waves done reading buf[cur] before re-stage
  }

  // ---- epilogue: per-lane 1/l, pack 4 consecutive d per store ----
  float inv = 1.0f / l_s;
  unsigned short* orow = Ob + (size_t)(b * 2048 + qrow) * 2048 + hd * 128;
#pragma unroll
  for (int dt = 0; dt < 4; ++dt)
#pragma unroll
    for (int g = 0; g < 4; ++g) {
      ushort4 wv;
      wv.x = f2bf(oa[dt][4 * g + 0] * inv);
      wv.y = f2bf(oa[dt][4 * g + 1] * inv);
      wv.z = f2bf(oa[dt][4 * g + 2] * inv);
      wv.w = f2bf(oa[dt][4 * g + 3] * inv);
      *(ushort4*)(orow + dt * 32 + 8 * g + 4 * hh2) = wv;
    }
}

extern "C" void kernel_launch(void* const* d_in, const int* in_sizes, int n_in,
                              void* d_out, int out_size, void* d_ws, size_t ws_size,
                              hipStream_t stream) {
  (void)in_sizes; (void)n_in; (void)out_size; (void)ws_size;
  const float* x  = (const float*)d_in[0];
  const float* fr = (const float*)d_in[1];
  // d_in[2] = mask: implemented as causal directly
  const float* wq = (const float*)d_in[3];
  const float* wk = (const float*)d_in[4];
  const float* wv = (const float*)d_in[5];
  const float* wo = (const float*)d_in[6];
  float* out = (float*)d_out;

  char* ws = (char*)d_ws;
  unsigned short* Xb    = (unsigned short*)(ws);                      // 16 MB
  unsigned short* WqkvT = (unsigned short*)(ws + (size_t)(16u << 20));// 16 MB, [n][k]
  unsigned short* WoT   = (unsigned short*)(ws + (size_t)(32u << 20));// 8 MB
  unsigned short* QKV   = (unsigned short*)(ws + (size_t)(40u << 20));// 32 MB (4096 x 4096)
  unsigned short* Vt    = (unsigned short*)(ws);                      // reuse Xb region
  unsigned short* Ob    = (unsigned short*)(ws + (size_t)(16u << 20));// reuse WqkvT region

  prep_k<<<11264, 256, 0, stream>>>(x, Xb, wq, wk, wv, wo, WqkvT, WoT);
  gemm256<true><<<dim3(16, 16), 512, 0, stream>>>(Xb, WqkvT, QKV, 4096, 4096, 2048);
  rope_tv_k<<<5120, 256, 0, stream>>>(QKV, fr, Vt);
  attn_k<<<dim3(16, 16, 2), 256, 0, stream>>>(QKV, Vt, Ob);
  gemm_bt<false><<<dim3(16, 32), 256, 0, stream>>>(Ob, WoT, out, 4096, 2048, 2048);
}

// Round 10
// 336.175 us; speedup vs baseline: 1.0517x; 1.0517x over previous
//
#include <hip/hip_runtime.h>

typedef short short8 __attribute__((ext_vector_type(8)));
typedef float v4f __attribute__((ext_vector_type(4)));
typedef float v16f __attribute__((ext_vector_type(16)));

#define LOG2E 1.4426950408889634f

__device__ __forceinline__ unsigned short f2bf(float f) {
  unsigned int u = __float_as_uint(f);
  u += 0x7fff + ((u >> 16) & 1);   // round-to-nearest-even
  return (unsigned short)(u >> 16);
}
__device__ __forceinline__ float b2f(unsigned short h) {
  return __uint_as_float(((unsigned int)h) << 16);
}
__device__ __forceinline__ void gl_lds16(const void* g, void* l) {
  __builtin_amdgcn_global_load_lds((const __attribute__((address_space(1))) void*)g,
                                   (__attribute__((address_space(3))) void*)l, 16, 0, 0);
}

// ---------------- fused prep: f32->bf16 cvt of X + 4 weight transposes ----------------
// grid 11264: [0,8192) cvt x; [8192,9216) wq; [9216,9728) wk; [9728,10240) wv; [10240,11264) wo
__global__ __launch_bounds__(256) void prep_k(const float* __restrict__ x,
                                              unsigned short* __restrict__ Xb,
                                              const float* __restrict__ wq,
                                              const float* __restrict__ wk,
                                              const float* __restrict__ wv,
                                              const float* __restrict__ wo,
                                              unsigned short* __restrict__ WqkvT,
                                              unsigned short* __restrict__ WoT) {
  __shared__ float tile[64][65];
  const int bid = blockIdx.x, t = threadIdx.x;
  if (bid < 8192) {
    int i = (bid * 256 + t) * 4;
    float4 v = *(const float4*)(x + i);
    ushort4 o;
    o.x = f2bf(v.x); o.y = f2bf(v.y); o.z = f2bf(v.z); o.w = f2bf(v.w);
    *(ushort4*)(Xb + i) = o;
    return;
  }
  const float* src; unsigned short* dst; int srcCols, bx, by;
  if (bid < 9216)      { int g = bid - 8192;  src = wq; dst = WqkvT;                         srcCols = 2048; bx = g & 31, by = g >> 5; }
  else if (bid < 9728) { int g = bid - 9216;  src = wk; dst = WqkvT + (size_t)2048 * 2048;   srcCols = 1024; bx = g & 15, by = g >> 4; }
  else if (bid < 10240){ int g = bid - 9728;  src = wv; dst = WqkvT + (size_t)3072 * 2048;   srcCols = 1024; bx = g & 15, by = g >> 4; }
  else                 { int g = bid - 10240; src = wo; dst = WoT;                           srcCols = 2048; bx = g & 31, by = g >> 5; }
  const int c0 = bx * 64;   // src col = dst row
  const int r0 = by * 64;   // src row = dst col
#pragma unroll
  for (int i = 0; i < 16; ++i) {
    int idx = t + i * 256; int r = idx >> 6, c = idx & 63;
    tile[r][c] = src[(size_t)(r0 + r) * srcCols + c0 + c];
  }
  __syncthreads();
#pragma unroll
  for (int i = 0; i < 16; ++i) {
    int idx = t + i * 256; int r = idx >> 6, c = idx & 63;
    dst[(size_t)(c0 + r) * 2048 + r0 + c] = f2bf(tile[c][r]);
  }
}

// ---------------- GEMM (128^2 tile, proven): C[M,N] = A[M,K] * Bt[N,K]^T ----------------
template <bool OUT_BF16>
__global__ __launch_bounds__(256) void gemm_bt(const unsigned short* __restrict__ A,
                                               const unsigned short* __restrict__ Bt,
                                               void* __restrict__ Cv,
                                               int M, int N, int K) {
  __shared__ __align__(16) unsigned short As[2][128 * 32];
  __shared__ __align__(16) unsigned short Bs[2][128 * 32];
  const int t = threadIdx.x;
  const int wave = t >> 6, lane = t & 63, quad = lane >> 4, l16 = lane & 15;
  const int tm = blockIdx.y * 128, tn = blockIdx.x * 128;
  const int wm = (wave >> 1) * 64, wn = (wave & 1) * 64;
  v4f acc[4][4];
#pragma unroll
  for (int i = 0; i < 4; ++i)
#pragma unroll
    for (int j = 0; j < 4; ++j) acc[i][j] = (v4f){0.f, 0.f, 0.f, 0.f};

  const int swz = (l16 >> 1) & 3;

  const int s0 = t, s1 = 256 + t;
  const unsigned short* pa0 = A + (size_t)(tm + (s0 >> 2)) * K + ((s0 & 3) ^ ((s0 >> 3) & 3)) * 8;
  const unsigned short* pa1 = A + (size_t)(tm + (s1 >> 2)) * K + ((s1 & 3) ^ ((s1 >> 3) & 3)) * 8;
  const unsigned short* pb0 = Bt + (size_t)(tn + (s0 >> 2)) * K + ((s0 & 3) ^ ((s0 >> 3) & 3)) * 8;
  const unsigned short* pb1 = Bt + (size_t)(tn + (s1 >> 2)) * K + ((s1 & 3) ^ ((s1 >> 3) & 3)) * 8;
  const int dOff0 = (wave * 64) * 8;
  const int dOff1 = (256 + wave * 64) * 8;

  gl_lds16(pa0, &As[0][dOff0]); gl_lds16(pa1, &As[0][dOff1]);
  gl_lds16(pb0, &Bs[0][dOff0]); gl_lds16(pb1, &Bs[0][dOff1]);
  pa0 += 32; pa1 += 32; pb0 += 32; pb1 += 32;

  const int nit = K >> 5;
  for (int it = 0; it < nit; ++it) {
    __syncthreads();
    const int cur = it & 1;
    if (it + 1 < nit) {
      const int nxt = cur ^ 1;
      gl_lds16(pa0, &As[nxt][dOff0]); gl_lds16(pa1, &As[nxt][dOff1]);
      gl_lds16(pb0, &Bs[nxt][dOff0]); gl_lds16(pb1, &Bs[nxt][dOff1]);
      pa0 += 32; pa1 += 32; pb0 += 32; pb1 += 32;
    }
    short8 af[4], bf[4];
#pragma unroll
    for (int mt = 0; mt < 4; ++mt)
      af[mt] = *(const short8*)(&As[cur][(wm + mt * 16 + l16) * 32 + (quad ^ swz) * 8]);
#pragma unroll
    for (int nt = 0; nt < 4; ++nt)
      bf[nt] = *(const short8*)(&Bs[cur][(wn + nt * 16 + l16) * 32 + (quad ^ swz) * 8]);
#pragma unroll
    for (int mt = 0; mt < 4; ++mt)
#pragma unroll
      for (int nt = 0; nt < 4; ++nt)
        acc[mt][nt] = __builtin_amdgcn_mfma_f32_16x16x32_bf16(af[mt], bf[nt], acc[mt][nt], 0, 0, 0);
  }

#pragma unroll
  for (int mt = 0; mt < 4; ++mt)
#pragma unroll
    for (int nt = 0; nt < 4; ++nt)
#pragma unroll
      for (int r = 0; r < 4; ++r) {
        int row = tm + wm + mt * 16 + quad * 4 + r;
        int col = tn + wn + nt * 16 + l16;
        float v = acc[mt][nt][r];
        if (OUT_BF16) ((unsigned short*)Cv)[(size_t)row * N + col] = f2bf(v);
        else          ((float*)Cv)[(size_t)row * N + col] = v;
      }
}

// ---------------- GEMM 256^2 tile, 8-wave, 4-phase, END-BARRIER-ONLY schedule ----------------
// R9 post-mortem: the start-of-phase barriers created a CU-wide convoy — all 8 waves did
// LDS reads, THEN all did MFMA, never overlapping (33% MfmaUtil = 512/1550 cyc/phase).
// Hazard audit shows start-barriers protect nothing: (RAW) each wave's vmcnt drains its own
// stages before P4's END barrier, so P1's reads (after it) see all stages; (WAR) every read
// drains at its phase's lgkm0 BEFORE the end barrier, and the overwriting STG issues only
// after a later end barrier. One barrier per phase -> waves skew within a phase -> wave A's
// MFMA overlaps wave B's ds_reads.
template <bool OUT_BF16>
__global__ __launch_bounds__(512, 2) void gemm256(const unsigned short* __restrict__ A,
                                                  const unsigned short* __restrict__ Bt,
                                                  void* __restrict__ Cv,
                                                  int M, int N, int K) {
  __shared__ __align__(16) unsigned short As[2][256 * 64];   // 64 KB
  __shared__ __align__(16) unsigned short Bs[2][256 * 64];   // 64 KB
  const int t = threadIdx.x;
  const int wave = t >> 6, lane = t & 63, quad = lane >> 4, l16 = lane & 15;
  const int wr = wave >> 2, wc = wave & 3;

  const int gx = N >> 8;
  int id = blockIdx.y * gridDim.x + blockIdx.x;
  const int nwg = gridDim.x * gridDim.y;
  id = (id & 7) * (nwg >> 3) + (id >> 3);
  const int tm = (id / gx) << 8, tn = (id % gx) << 8;

  v4f acc[8][4];
#pragma unroll
  for (int i = 0; i < 8; ++i)
#pragma unroll
    for (int j = 0; j < 4; ++j) acc[i][j] = (v4f){0.f, 0.f, 0.f, 0.f};

  const int s0 = t, s1 = 512 + t;
  const size_t hA = (size_t)128 * K;
  const unsigned short* a0 = A + (size_t)(tm + (s0 >> 3)) * K + ((s0 & 7) ^ ((s0 >> 3) & 7)) * 8;
  const unsigned short* a1 = A + (size_t)(tm + (s1 >> 3)) * K + ((s1 & 7) ^ ((s1 >> 3) & 7)) * 8;
  const unsigned short* b0 = Bt + (size_t)(tn + (s0 >> 3)) * K + ((s0 & 7) ^ ((s0 >> 3) & 7)) * 8;
  const unsigned short* b1 = Bt + (size_t)(tn + (s1 >> 3)) * K + ((s1 & 7) ^ ((s1 >> 3) & 7)) * 8;
  const int d0 = (wave * 64) * 8;
  const int d1 = (512 + wave * 64) * 8;

#define STG_A(buf, h, koff)                                         \
  do {                                                              \
    gl_lds16(a0 + (size_t)(h) * hA + (koff), &As[buf][(h) * 8192 + d0]); \
    gl_lds16(a1 + (size_t)(h) * hA + (koff), &As[buf][(h) * 8192 + d1]); \
  } while (0)
#define STG_B(buf, h, koff)                                         \
  do {                                                              \
    gl_lds16(b0 + (size_t)(h) * hA + (koff), &Bs[buf][(h) * 8192 + d0]); \
    gl_lds16(b1 + (size_t)(h) * hA + (koff), &Bs[buf][(h) * 8192 + d1]); \
  } while (0)

  const int aBase = (wr * 128 + l16) * 64;
  const int bBase = (wc * 64 + l16) * 64;
  const int c0 = (quad ^ (l16 & 7)) * 8;
  const int c1 = ((4 + quad) ^ (l16 & 7)) * 8;

  const int nkt = K >> 6;

  STG_A(0, 0, 0); STG_A(0, 1, 0);
  STG_B(0, 0, 0); STG_B(0, 1, 0);
  STG_B(1, 0, 64); STG_A(1, 0, 64);
  asm volatile("s_waitcnt vmcnt(4)" ::: "memory");   // kt0's 8 loads landed
  __builtin_amdgcn_s_barrier();

  short8 af[4], bf[4];
  for (int kt = 0; kt < nkt; ++kt) {
    const int cur = kt & 1, nxt = cur ^ 1;
    const int koff = kt << 6;

    // ---------- phase 1: Q00 (A-lo x B-lo); stage h1(kt+1) ----------
#pragma unroll
    for (int m = 0; m < 4; ++m)
      af[m] = *(const short8*)(&As[cur][aBase + m * 1024 + ((kt & 1) ? c1 : c0)]);
    // NOTE: af layout identical to R8 — read both k-chunks per row:
    // (re-expanded below; the line above is replaced by the full 2-chunk reads)
    short8 af2[4], bf2[4];
#pragma unroll
    for (int m = 0; m < 4; ++m) {
      af[m]  = *(const short8*)(&As[cur][aBase + m * 1024 + c0]);
      af2[m] = *(const short8*)(&As[cur][aBase + m * 1024 + c1]);
    }
#pragma unroll
    for (int n = 0; n < 2; ++n) {
      bf[n]  = *(const short8*)(&Bs[cur][bBase + n * 1024 + c0]);
      bf2[n] = *(const short8*)(&Bs[cur][bBase + n * 1024 + c1]);
    }
    if (kt + 1 < nkt) { STG_A(nxt, 1, koff + 64); STG_B(nxt, 1, koff + 64); }
    asm volatile("s_waitcnt lgkmcnt(0)" ::: "memory");
    __builtin_amdgcn_s_setprio(1);
#pragma unroll
    for (int m = 0; m < 4; ++m)
#pragma unroll
      for (int n = 0; n < 2; ++n) {
        acc[m][n] = __builtin_amdgcn_mfma_f32_16x16x32_bf16(af[m],  bf[n],  acc[m][n], 0, 0, 0);
        acc[m][n] = __builtin_amdgcn_mfma_f32_16x16x32_bf16(af2[m], bf2[n], acc[m][n], 0, 0, 0);
      }
    __builtin_amdgcn_s_setprio(0);
    __builtin_amdgcn_s_barrier();

    // ---------- phase 2: Q01 (A-lo x B-hi) ----------
#pragma unroll
    for (int n = 2; n < 4; ++n) {
      bf[n]  = *(const short8*)(&Bs[cur][bBase + n * 1024 + c0]);
      bf2[n] = *(const short8*)(&Bs[cur][bBase + n * 1024 + c1]);
    }
    asm volatile("s_waitcnt lgkmcnt(0)" ::: "memory");
    __builtin_amdgcn_s_setprio(1);
#pragma unroll
    for (int m = 0; m < 4; ++m)
#pragma unroll
      for (int n = 2; n < 4; ++n) {
        acc[m][n] = __builtin_amdgcn_mfma_f32_16x16x32_bf16(af[m],  bf[n],  acc[m][n], 0, 0, 0);
        acc[m][n] = __builtin_amdgcn_mfma_f32_16x16x32_bf16(af2[m], bf2[n], acc[m][n], 0, 0, 0);
      }
    __builtin_amdgcn_s_setprio(0);
    __builtin_amdgcn_s_barrier();

    // ---------- phase 3: Q10 (A-hi x B-lo); stage B-h0(kt+2) ----------
#pragma unroll
    for (int m = 0; m < 4; ++m) {
      af[m]  = *(const short8*)(&As[cur][aBase + (4 + m) * 1024 + c0]);
      af2[m] = *(const short8*)(&As[cur][aBase + (4 + m) * 1024 + c1]);
    }
    if (kt + 2 < nkt) STG_B(cur, 0, koff + 128);
    asm volatile("s_waitcnt lgkmcnt(0)" ::: "memory");
    __builtin_amdgcn_s_setprio(1);
#pragma unroll
    for (int m = 0; m < 4; ++m)
#pragma unroll
      for (int n = 0; n < 2; ++n) {
        acc[4 + m][n] = __builtin_amdgcn_mfma_f32_16x16x32_bf16(af[m],  bf[n],  acc[4 + m][n], 0, 0, 0);
        acc[4 + m][n] = __builtin_amdgcn_mfma_f32_16x16x32_bf16(af2[m], bf2[n], acc[4 + m][n], 0, 0, 0);
      }
    __builtin_amdgcn_s_setprio(0);
    __builtin_amdgcn_s_barrier();

    // ---------- phase 4: Q11 (A-hi x B-hi); stage A-h0(kt+2) ----------
    if (kt + 2 < nkt) {
      STG_A(cur, 0, koff + 128);
      asm volatile("s_waitcnt vmcnt(4)" ::: "memory");   // h1(kt+1) landed; kt+2 h0s in flight
    } else {
      asm volatile("s_waitcnt vmcnt(0)" ::: "memory");
    }
    __builtin_amdgcn_s_setprio(1);
#pragma unroll
    for (int m = 0; m < 4; ++m)
#pragma unroll
      for (int n = 2; n < 4; ++n) {
        acc[4 + m][n] = __builtin_amdgcn_mfma_f32_16x16x32_bf16(af[m],  bf[n],  acc[4 + m][n], 0, 0, 0);
        acc[4 + m][n] = __builtin_amdgcn_mfma_f32_16x16x32_bf16(af2[m], bf2[n], acc[4 + m][n], 0, 0, 0);
      }
    __builtin_amdgcn_s_setprio(0);
    __builtin_amdgcn_s_barrier();
  }
#undef STG_A
#undef STG_B

#pragma unroll
  for (int mf = 0; mf < 8; ++mf)
#pragma unroll
    for (int nf = 0; nf < 4; ++nf)
#pragma unroll
      for (int r = 0; r < 4; ++r) {
        int row = tm + wr * 128 + mf * 16 + quad * 4 + r;
        int col = tn + wc * 64 + nf * 16 + l16;
        float v = acc[mf][nf][r];
        if (OUT_BF16) ((unsigned short*)Cv)[(size_t)row * N + col] = f2bf(v);
        else          ((float*)Cv)[(size_t)row * N + col] = v;
      }
}

// ---------------- fused RoPE (Q,K dwords) + V transpose (disjoint QKV columns) ----------------
// grid 5120: [0,4096) rope rows; [4096,5120) V-transpose tiles.
__global__ __launch_bounds__(256) void rope_tv_k(unsigned short* __restrict__ qkv,
                                                 const float* __restrict__ freqs,
                                                 unsigned short* __restrict__ vt) {
  __shared__ unsigned short tile[64][65];
  const int bid = blockIdx.x, t = threadIdx.x;
  if (bid < 4096) {
    const int bs = bid;                 // b*2048 + s
    const int s = bs & 2047;
    const float qscale = 0.08838834764831845f;  // 1/sqrt(128)
    unsigned int* row = (unsigned int*)(qkv + (size_t)bs * 4096);
    const float2* fr2 = (const float2*)(freqs + s * 128);
#pragma unroll
    for (int k = 0; k < 6; ++k) {
      int d = t + k * 256;              // dword index 0..1535 (Q,K only; V untouched)
      float sc = (d < 1024) ? qscale : 1.0f;
      float2 cs = fr2[d & 63];          // (cos, sin)
      unsigned int w = row[d];
      float x0 = b2f((unsigned short)(w & 0xffffu));
      float x1 = b2f((unsigned short)(w >> 16));
      float y0 = (x0 * cs.y - x1 * cs.x) * sc;
      float y1 = (x0 * cs.x + x1 * cs.y) * sc;
      row[d] = ((unsigned int)f2bf(y1) << 16) | (unsigned int)f2bf(y0);
    }
    return;
  }
  const int g = bid - 4096;
  const int s0 = (g & 31) * 64, d0 = ((g >> 5) & 1) * 64;
  const int bk = g >> 6; const int b = bk >> 3, kv = bk & 7;
#pragma unroll
  for (int i = 0; i < 16; ++i) {
    int idx = t + i * 256; int r = idx >> 6, c = idx & 63;
    tile[r][c] = qkv[(size_t)(b * 2048 + s0 + r) * 4096 + 3072 + kv * 128 + d0 + c];
  }
  __syncthreads();
#pragma unroll
  for (int i = 0; i < 16; ++i) {
    int idx = t + i * 256; int r = idx >> 6, c = idx & 63;
    vt[((size_t)bk * 128 + d0 + r) * 2048 + s0 + c] = tile[c][r];
  }
}

// ---------------- causal flash attention, 32x32 MFMA, O^T, KVBLK=64 (R5-proven) ----------------
__global__ __launch_bounds__(256, 2) void attn_k(const unsigned short* __restrict__ qkv,
                                                 const unsigned short* __restrict__ vt,
                                                 unsigned short* __restrict__ Ob) {
  __shared__ __align__(16) unsigned short Ks[2][64 * 128];   // [key][d], 16 chunks/row
  __shared__ __align__(16) unsigned short Vs[2][128 * 64];   // [d][key],  8 chunks/row
  const int t = threadIdx.x, wave = t >> 6, lane = t & 63;
  const int l31 = lane & 31, hh2 = lane >> 5;
  const int hd = blockIdx.y, b = blockIdx.z;
  const int qblk = b ? blockIdx.x : 15 - blockIdx.x;   // complementary co-resident pairs
  const int kv = hd >> 1;
  const int q0 = qblk * 128;
  const int qrel = wave * 32 + l31;
  const int qrow = q0 + qrel;

  auto stage = [&](int jt, int buf) {
#pragma unroll
    for (int issue = 0; issue < 4; ++issue) {
      int s = issue * 256 + t;                 // K slot 0..1023
      int row = s >> 4;                        // key 0..63
      int src = ((s & 15) ^ (row & 15)) * 8;   // pre-swizzled source chunk
      gl_lds16(qkv + (size_t)(b * 2048 + jt * 64 + row) * 4096 + 2048 + kv * 128 + src,
               &Ks[buf][(issue * 256 + wave * 64) * 8]);
    }
#pragma unroll
    for (int issue = 0; issue < 4; ++issue) {
      int s = issue * 256 + t;                 // V slot 0..1023
      int row = s >> 3;                        // d 0..127
      int src = ((s & 7) ^ (row & 7)) * 8;
      gl_lds16(vt + ((size_t)(b * 8 + kv) * 128 + row) * 2048 + jt * 64 + src,
               &Vs[buf][(issue * 256 + wave * 64) * 8]);
    }
  };

  short8 qf[8];
  {
    const unsigned short* qp = qkv + (size_t)(b * 2048 + qrow) * 4096 + hd * 128 + hh2 * 8;
#pragma unroll
    for (int ks = 0; ks < 8; ++ks) qf[ks] = *(const short8*)(qp + ks * 16);
  }
  stage(0, 0);

  v16f oa[4];
#pragma unroll
  for (int i = 0; i < 4; ++i)
#pragma unroll
    for (int r = 0; r < 16; ++r) oa[i][r] = 0.f;
  float m_s = -3.0e38f, l_s = 0.f;

  const int ntl = 2 * (qblk + 1);   // 64-key tiles
  for (int jt = 0; jt < ntl; ++jt) {
    const int cur = jt & 1;
    if (jt + 1 < ntl) {
      stage(jt + 1, cur ^ 1);
      asm volatile("s_waitcnt vmcnt(8)" ::: "memory");   // tile jt landed; jt+1 in flight
    } else {
      asm volatile("s_waitcnt vmcnt(0)" ::: "memory");
    }
    __builtin_amdgcn_s_barrier();

    // ---- QK^T: S^T tiles, rows = keys (kt*32 + map), cols = q (l31) ----
    v16f st[2];
#pragma unroll
    for (int i = 0; i < 2; ++i)
#pragma unroll
      for (int r = 0; r < 16; ++r) st[i][r] = 0.f;
#pragma unroll
    for (int ks = 0; ks < 8; ++ks)
#pragma unroll
      for (int kt = 0; kt < 2; ++kt) {
        int row = kt * 32 + l31;
        short8 kf = *(const short8*)(
            &Ks[cur][row * 128 + (((ks * 2 + hh2) ^ (row & 15)) * 8)]);
        st[kt] = __builtin_amdgcn_mfma_f32_32x32x16_bf16(kf, qf[ks], st[kt], 0, 0, 0);
      }

    // ---- mask (only tiles overlapping the diagonal) + row max ----
    float mx0 = -3.0e38f, mx1 = -3.0e38f;
    if (jt >= 2 * qblk) {
      const int rel = qrel - (jt * 64 - q0);   // key-local threshold
#pragma unroll
      for (int kt = 0; kt < 2; ++kt)
#pragma unroll
        for (int r = 0; r < 16; ++r) {
          int key = kt * 32 + (r & 3) + 8 * (r >> 2) + 4 * hh2;
          float v = st[kt][r];
          if (key > rel) v = -1.0e30f;
          st[kt][r] = v;
          if (r & 1) mx1 = fmaxf(mx1, v); else mx0 = fmaxf(mx0, v);
        }
    } else {
#pragma unroll
      for (int kt = 0; kt < 2; ++kt)
#pragma unroll
        for (int r = 0; r < 16; ++r) {
          if (r & 1) mx1 = fmaxf(mx1, st[kt][r]); else mx0 = fmaxf(mx0, st[kt][r]);
        }
    }
    float mx = fmaxf(mx0, mx1);
    mx = fmaxf(mx, __shfl_xor(mx, 32));   // combine the two key-halves of this qrow

    // ---- defer-max rescale (rare) ----
    if (__ballot(mx > m_s + 8.0f)) {
      float mn = fmaxf(m_s, mx);
      float alpha = exp2f((m_s - mn) * LOG2E);
      m_s = mn;
#pragma unroll
      for (int i = 0; i < 4; ++i)
#pragma unroll
        for (int r = 0; r < 16; ++r) oa[i][r] *= alpha;
      l_s *= alpha;
    }

    // ---- exp + pack P to bf16 dwords ----
    float lt0 = 0.f, lt1 = 0.f;
    unsigned int PD[2][8];
#pragma unroll
    for (int kt = 0; kt < 2; ++kt)
#pragma unroll
      for (int j = 0; j < 8; ++j) {
        float p0 = exp2f((st[kt][2 * j]     - m_s) * LOG2E);
        float p1 = exp2f((st[kt][2 * j + 1] - m_s) * LOG2E);
        lt0 += p0; lt1 += p1;
        unsigned int pd;
        asm("v_cvt_pk_bf16_f32 %0, %1, %2" : "=v"(pd) : "v"(p0), "v"(p1));
        PD[kt][j] = pd;
      }
    float lt = lt0 + lt1;
    lt += __shfl_xor(lt, 32);
    l_s += lt;

    // ---- exchange complementary key-halves (lane l <-> l+32) ----
    unsigned int XD[2][8];
#pragma unroll
    for (int kt = 0; kt < 2; ++kt)
#pragma unroll
      for (int j = 0; j < 8; ++j) XD[kt][j] = __shfl_xor(PD[kt][j], 32);

    // ---- PV: O^T += V' * P^T (contraction over 64 keys = 4 k-steps) ----
#pragma unroll
    for (int ks = 0; ks < 4; ++ks) {
      const int tt = ks >> 1, w4 = (ks & 1) * 4;
      union { unsigned int u[4]; short8 s8; } pf;
      pf.u[0] = hh2 ? XD[tt][w4 + 2] : PD[tt][w4 + 0];
      pf.u[1] = hh2 ? XD[tt][w4 + 3] : PD[tt][w4 + 1];
      pf.u[2] = hh2 ? PD[tt][w4 + 2] : XD[tt][w4 + 0];
      pf.u[3] = hh2 ? PD[tt][w4 + 3] : XD[tt][w4 + 1];
#pragma unroll
      for (int dt = 0; dt < 4; ++dt) {
        int row = dt * 32 + l31;
        short8 vf = *(const short8*)(
            &Vs[cur][row * 64 + (((ks * 2 + hh2) ^ (row & 7)) * 8)]);
        oa[dt] = __builtin_amdgcn_mfma_f32_32x32x16_bf16(vf, pf.s8, oa[dt], 0, 0, 0);
      }
    }
    __builtin_amdgcn_s_barrier();   // all waves done reading buf[cur] before re-stage
  }

  // ---- epilogue: per-lane 1/l, pack 4 consecutive d per store ----
  float inv = 1.0f / l_s;
  unsigned short* orow = Ob + (size_t)(b * 2048 + qrow) * 2048 + hd * 128;
#pragma unroll
  for (int dt = 0; dt < 4; ++dt)
#pragma unroll
    for (int g = 0; g < 4; ++g) {
      ushort4 wv;
      wv.x = f2bf(oa[dt][4 * g + 0] * inv);
      wv.y = f2bf(oa[dt][4 * g + 1] * inv);
      wv.z = f2bf(oa[dt][4 * g + 2] * inv);
      wv.w = f2bf(oa[dt][4 * g + 3] * inv);
      *(ushort4*)(orow + dt * 32 + 8 * g + 4 * hh2) = wv;
    }
}

extern "C" void kernel_launch(void* const* d_in, const int* in_sizes, int n_in,
                              void* d_out, int out_size, void* d_ws, size_t ws_size,
                              hipStream_t stream) {
  (void)in_sizes; (void)n_in; (void)out_size; (void)ws_size;
  const float* x  = (const float*)d_in[0];
  const float* fr = (const float*)d_in[1];
  // d_in[2] = mask: implemented as causal directly
  const float* wq = (const float*)d_in[3];
  const float* wk = (const float*)d_in[4];
  const float* wv = (const float*)d_in[5];
  const float* wo = (const float*)d_in[6];
  float* out = (float*)d_out;

  char* ws = (char*)d_ws;
  unsigned short* Xb    = (unsigned short*)(ws);                      // 16 MB
  unsigned short* WqkvT = (unsigned short*)(ws + (size_t)(16u << 20));// 16 MB, [n][k]
  unsigned short* WoT   = (unsigned short*)(ws + (size_t)(32u << 20));// 8 MB
  unsigned short* QKV   = (unsigned short*)(ws + (size_t)(40u << 20));// 32 MB (4096 x 4096)
  unsigned short* Vt    = (unsigned short*)(ws);                      // reuse Xb region
  unsigned short* Ob    = (unsigned short*)(ws + (size_t)(16u << 20));// reuse WqkvT region

  prep_k<<<11264, 256, 0, stream>>>(x, Xb, wq, wk, wv, wo, WqkvT, WoT);
  gemm256<true><<<dim3(16, 16), 512, 0, stream>>>(Xb, WqkvT, QKV, 4096, 4096, 2048);
  rope_tv_k<<<5120, 256, 0, stream>>>(QKV, fr, Vt);
  attn_k<<<dim3(16, 16, 2), 256, 0, stream>>>(QKV, Vt, Ob);
  gemm_bt<false><<<dim3(16, 32), 256, 0, stream>>>(Ob, WoT, out, 4096, 2048, 2048);
}